// Round 12
// baseline (152.454 us; speedup 1.0000x reference)
//
#include <hip/hip_runtime.h>

#define NB     50000
#define NB4    12500
#define BATCH  256
#define NCYC   20000
#define QSCALE  (127.0f / 3.14159265358979f)
#define DQSCALE (3.14159265358979f / 127.0f)
#define OUTSCALE (1.0f / ((float)NCYC * (float)BATCH))

typedef float f32x4 __attribute__((ext_vector_type(4)));

// Fast atan2 with QSCALE folded in: returns atan2(y,x) * (127/pi).
// Hastings deg-9 odd minimax on [0,1], max err ~1e-5 rad (4e-4 int8 code
// flips => ~1e-7 relative error on the final mean).
__device__ __forceinline__ float fast_atan2q(float y, float x) {
    const float ax = __builtin_fabsf(x);
    const float ay = __builtin_fabsf(y);
    const float mx = fmaxf(ax, ay);
    const float mn = fminf(ax, ay);
    const float t  = mn * __builtin_amdgcn_rcpf(mx);   // in [0,1]
    const float t2 = t * t;
    // coefficients pre-scaled by 127/pi
    float p = fmaf(t2, fmaf(t2, fmaf(t2, fmaf(t2,
                  0.84219761f, -3.44137383f), 7.28200966f), -13.35163894f),
                  40.42416382f);
    p *= t;
    p = (ay > ax) ? (63.5f - p) : p;     // 127/pi * (pi/2 - atan)
    p = (x < 0.0f) ? (127.0f - p) : p;   // 127/pi * (pi - atan)
    return copysignf(p, y);
}

// ---- kernel 1: transpose + atan2 + int8 quantize -> th[NB][BATCH],
//      R5 structure (41.4 us measured) with ONE change: c/s loads are
//      NONTEMPORAL (nt bit, cache-bypass) to probe/avoid the ~2.5 TB/s
//      cached-read concurrency cap (7 schedule variants all pinned there
//      with HBM/VALU/LDS idle). row_start precompute unchanged. ----------
__global__ __launch_bounds__(256) void theta_k(
        const float4* __restrict__ c4, const float4* __restrict__ s4,
        signed char* __restrict__ th, int* __restrict__ row_start,
        const int* __restrict__ rows, int E) {
    __shared__ signed char t[64][68];       // [b_local][nb_local], 68 = 4*17
    const int u = threadIdx.x;

    if (blockIdx.y == 0) {
        const int g = blockIdx.x * 256 + u;
        if (g <= NCYC) {
            int lo = 0, hi = E;
            while (lo < hi) { const int m = (lo + hi) >> 1; if (rows[m] < g) lo = m + 1; else hi = m; }
            row_start[g] = lo;
        }
    }

    const int col4 = u & 15;                // nb4 within tile
    const int brow = u >> 4;                // 0..15
    const int x4   = blockIdx.x * 16 + col4;
    const int bb   = blockIdx.y * 64;

    if (x4 < NB4) {
        #pragma unroll
        for (int j = 0; j < 4; ++j) {
            const int bl = brow + 16 * j;   // b_local 0..63
            const f32x4 vc = __builtin_nontemporal_load(
                reinterpret_cast<const f32x4*>(&c4[(size_t)(bb + bl) * NB4 + x4]));
            const f32x4 vs = __builtin_nontemporal_load(
                reinterpret_cast<const f32x4*>(&s4[(size_t)(bb + bl) * NB4 + x4]));
            char4 q;
            q.x = (signed char)__float2int_rn(fast_atan2q(vs[0], vc[0]));
            q.y = (signed char)__float2int_rn(fast_atan2q(vs[1], vc[1]));
            q.z = (signed char)__float2int_rn(fast_atan2q(vs[2], vc[2]));
            q.w = (signed char)__float2int_rn(fast_atan2q(vs[3], vc[3]));
            *reinterpret_cast<char4*>(&t[bl][4 * col4]) = q;
        }
    }
    __syncthreads();
    // store phase: 16 lanes cover 64 consecutive b (64B) per nb
    const int g   = u & 15;                 // char4 group along b
    const int nb0 = u >> 4;                 // 0..15
    #pragma unroll
    for (int j = 0; j < 4; ++j) {
        const int nbl = nb0 + 16 * j;       // 0..63
        const int nb  = blockIdx.x * 64 + nbl;
        if (nb < NB) {
            char4 v;
            v.x = t[4 * g + 0][nbl];
            v.y = t[4 * g + 1][nbl];
            v.z = t[4 * g + 2][nbl];
            v.w = t[4 * g + 3][nbl];
            *reinterpret_cast<char4*>(&th[(size_t)nb * BATCH + bb + 4 * g]) = v;
        }
    }
}

// ---- kernel 2: wave per row (4/block), precomputed bounds, NO fences,
//      one partial per block ----------------------------------------------
__global__ __launch_bounds__(256) void kvl3_k(
        const signed char* __restrict__ th,
        const float* __restrict__ signs, const int* __restrict__ inds,
        const int* __restrict__ row_start,
        float* __restrict__ partials) {
    __shared__ float wsum[4];
    const int tid  = threadIdx.x;
    const int wave = tid >> 6;
    const int lane = tid & 63;
    const int r    = blockIdx.x * 4 + wave;           // < NCYC (5000*4)
    const int start = row_start[r];
    const int end   = row_start[r + 1];

    float a0 = 0.f, a1 = 0.f, a2 = 0.f, a3 = 0.f;
    int e = start;
    for (; e + 2 <= end; e += 2) {
        const int   i0 = inds[e],  i1 = inds[e + 1];
        const float g0 = signs[e] * DQSCALE, g1 = signs[e + 1] * DQSCALE;
        const unsigned int u0 = *reinterpret_cast<const unsigned int*>(&th[(size_t)i0 * BATCH + lane * 4]);
        const unsigned int u1 = *reinterpret_cast<const unsigned int*>(&th[(size_t)i1 * BATCH + lane * 4]);
        a0 += g0 * (float)(signed char)(u0      ) + g1 * (float)(signed char)(u1      );
        a1 += g0 * (float)(signed char)(u0 >>  8) + g1 * (float)(signed char)(u1 >>  8);
        a2 += g0 * (float)(signed char)(u0 >> 16) + g1 * (float)(signed char)(u1 >> 16);
        a3 += g0 * (float)(signed char)(u0 >> 24) + g1 * (float)(signed char)(u1 >> 24);
    }
    if (e < end) {
        const float g0 = signs[e] * DQSCALE;
        const unsigned int u0 = *reinterpret_cast<const unsigned int*>(&th[(size_t)inds[e] * BATCH + lane * 4]);
        a0 += g0 * (float)(signed char)(u0      );
        a1 += g0 * (float)(signed char)(u0 >>  8);
        a2 += g0 * (float)(signed char)(u0 >> 16);
        a3 += g0 * (float)(signed char)(u0 >> 24);
    }
    float v = fabsf(a0) + fabsf(a1) + fabsf(a2) + fabsf(a3);
    #pragma unroll
    for (int off = 32; off > 0; off >>= 1)
        v += __shfl_down(v, off, 64);
    if (lane == 0) wsum[wave] = v;
    __syncthreads();
    if (tid == 0)
        partials[blockIdx.x] = wsum[0] + wsum[1] + wsum[2] + wsum[3];
}

// ---- kernel 3: single block reduces 5000 block partials -> out[0] ---------
__global__ __launch_bounds__(1024) void reduce_k(
        const float* __restrict__ partials, float* __restrict__ out) {
    const int tid = threadIdx.x;
    float v = 0.f;
    for (int i = tid; i < NCYC / 4; i += 1024) v += partials[i];
    #pragma unroll
    for (int off = 32; off > 0; off >>= 1)
        v += __shfl_down(v, off, 64);
    __shared__ float wsum[16];
    if ((tid & 63) == 0) wsum[tid >> 6] = v;
    __syncthreads();
    if (tid == 0) {
        float t = 0.f;
        #pragma unroll
        for (int w = 0; w < 16; ++w) t += wsum[w];
        out[0] = t * OUTSCALE;
    }
}

// ---- fallback (no workspace): direct strided gather -----------------------
__global__ void zero_out_k(float* out) { if (threadIdx.x == 0) out[0] = 0.0f; }

__global__ __launch_bounds__(256) void kvl_fallback_k(
        const float* __restrict__ c, const float* __restrict__ s,
        const float* __restrict__ signs, const int* __restrict__ inds,
        const int* __restrict__ rows, int E, float* __restrict__ out) {
    const int r = blockIdx.x;
    int lo = 0, hi = E;
    while (lo < hi) { const int m = (lo + hi) >> 1; if (rows[m] < r) lo = m + 1; else hi = m; }
    const int start = lo;
    hi = E;
    while (lo < hi) { const int m = (lo + hi) >> 1; if (rows[m] <= r) lo = m + 1; else hi = m; }
    const int end = lo;
    const int tid = threadIdx.x;
    float acc = 0.f;
    for (int e = start; e < end; ++e) {
        const int idx = inds[e];
        const float sg = signs[e];
        acc += atan2f(sg * s[(size_t)tid * NB + idx], c[(size_t)tid * NB + idx]);
    }
    float v = fabsf(acc);
    #pragma unroll
    for (int off = 32; off > 0; off >>= 1)
        v += __shfl_down(v, off, 64);
    __shared__ float wsum[4];
    if ((tid & 63) == 0) wsum[tid >> 6] = v;
    __syncthreads();
    if (tid == 0)
        atomicAdd(out, (wsum[0] + wsum[1] + wsum[2] + wsum[3]) *
                       (1.0f / ((float)NCYC * (float)BATCH)));
}

extern "C" void kernel_launch(void* const* d_in, const int* in_sizes, int n_in,
                              void* d_out, int out_size, void* d_ws, size_t ws_size,
                              hipStream_t stream) {
    const float* c       = (const float*)d_in[0];
    const float* s       = (const float*)d_in[1];
    const float* cysigns = (const float*)d_in[2];
    const int*   cyinds  = (const int*)d_in[3];
    const int*   cyrows  = (const int*)d_in[4];
    const int    E       = in_sizes[2];   // 160000
    float* out = (float*)d_out;

    const size_t th_bytes = (size_t)NB * BATCH;            // 12.8 MB int8
    const size_t rs_bytes = (size_t)(NCYC + 1) * sizeof(int);
    const size_t pa_bytes = (size_t)(NCYC / 4) * sizeof(float);
    const size_t need = th_bytes + rs_bytes + pa_bytes;
    if (ws_size >= need) {
        signed char* th   = (signed char*)d_ws;
        int* row_start    = (int*)(th + th_bytes);
        float* partials   = (float*)((char*)row_start + rs_bytes);

        dim3 tg((NB4 + 15) / 16, BATCH / 64);              // (782, 4)
        theta_k<<<tg, 256, 0, stream>>>((const float4*)c, (const float4*)s,
                                        th, row_start, cyrows, E);
        kvl3_k<<<NCYC / 4, 256, 0, stream>>>(th, cysigns, cyinds, row_start,
                                             partials);
        reduce_k<<<1, 1024, 0, stream>>>(partials, out);
    } else {
        zero_out_k<<<1, 64, 0, stream>>>(out);
        kvl_fallback_k<<<NCYC, 256, 0, stream>>>(c, s, cysigns, cyinds, cyrows, E, out);
    }
}